// Round 7
// baseline (683.322 us; speedup 1.0000x reference)
//
#include <hip/hip_runtime.h>
#include <hip/hip_bf16.h>
#include <stdint.h>

#define EN    8
#define DIN   512
#define HID   1024
#define BATCH 16384
#define LN_EPS 1e-5f

typedef __bf16   bf16x8 __attribute__((ext_vector_type(8)));
typedef float    f32x4  __attribute__((ext_vector_type(4)));
typedef uint16_t u16x8  __attribute__((ext_vector_type(8)));
typedef uint16_t u16x4  __attribute__((ext_vector_type(4)));
typedef float    fl4    __attribute__((ext_vector_type(4)));

__device__ __forceinline__ uint16_t f2bf(float f) {
  uint32_t x = __builtin_bit_cast(uint32_t, f);
  uint32_t r = (x + 0x7fffu + ((x >> 16) & 1u)) >> 16;  // RNE
  return (uint16_t)r;
}
__device__ __forceinline__ float bf2f(uint16_t u) {
  return __builtin_bit_cast(float, (uint32_t)u << 16);
}

__device__ __forceinline__ void gload16(const uint16_t* g, char* lds_d) {
  __builtin_amdgcn_global_load_lds(
      (const __attribute__((address_space(1))) uint32_t*)g,
      (__attribute__((address_space(3))) uint32_t*)lds_d, 16, 0, 0);
}

__device__ __forceinline__ f32x4 MF(bf16x8 a, bf16x8 b, f32x4 c) {
  return __builtin_amdgcn_mfma_f32_16x16x32_bf16(a, b, c, 0, 0, 0);
}

// Sync helpers: NO "memory" clobber anywhere (a memory-clobber asm makes the
// AMDGPU backend insert s_waitcnt vmcnt(0) lgkmcnt(0) before it -> hidden full
// drain at every barrier, which killed R3/R5/R6). Order is pinned with
// sched_barrier(0) (compile-time only).
__device__ __forceinline__ void BAR() {
  __builtin_amdgcn_s_barrier();
  __builtin_amdgcn_sched_barrier(0);
}
#define WAIT_VM(n) do { asm volatile("s_waitcnt vmcnt(" #n ")"); \
                        __builtin_amdgcn_sched_barrier(0); } while (0)

// ---------------- conversion: fp32 -> bf16 ----------------
__global__ __launch_bounds__(256) void cvt_bf16(const float* __restrict__ src,
                                                uint16_t* __restrict__ dst, long n) {
  long i = ((long)blockIdx.x * 256 + threadIdx.x) * 4;
  if (i >= n) return;
  fl4 v = *(const fl4*)(src + i);
  u16x4 o;
  #pragma unroll
  for (int j = 0; j < 4; ++j) o[j] = f2bf(v[j]);
  *(u16x4*)(dst + i) = o;
}

// ---------------- transpose + convert: [E][R][C] fp32 -> [E][C][R] bf16 ----------------
__global__ __launch_bounds__(256) void transpose_cvt(const float* __restrict__ src,
                                                     uint16_t* __restrict__ dst,
                                                     int R, int C) {
  __shared__ float tile[32][33];
  const int e = blockIdx.z;
  const int c0 = blockIdx.x * 32;
  const int r0 = blockIdx.y * 32;
  const int tx = threadIdx.x & 31, ty = threadIdx.x >> 5;
  const float* s = src + (size_t)e * R * C;
  uint16_t*    d = dst + (size_t)e * R * C;
  #pragma unroll
  for (int i = 0; i < 32; i += 8)
    tile[ty + i][tx] = s[(size_t)(r0 + ty + i) * C + (c0 + tx)];
  __syncthreads();
  #pragma unroll
  for (int i = 0; i < 32; i += 8)
    d[(size_t)(c0 + ty + i) * R + (r0 + tx)] = f2bf(tile[tx][ty + i]);
}

// ============== 256x256 8-phase GEMM (m201 ledger, clobber-free sync) ==============
// C[e][M][HID] = A[e][M][K] * Bt[e][HID][K]^T + bias.  512 thr = 8 waves (2M x 4N),
// wave tile 128x64, BK=64.  LDS 128 KiB = 2 dbuf x 4 windows x 16 KiB, windows in
// CONSUMPTION order: [w0: A rows{0-63,128-191} | w1: B cols 0-127 |
//                     w2: B cols 128-255 | w3: A rows{64-127,192-255}].
// Rows stored as 128B lines, unit u at phys u ^ (row&7)  (R3/R6-proven 0-conflict).
// Stage window H=P+7 at global phase P (WAR-safe); vmcnt(6) once per K-tile (RAW).
__global__ __launch_bounds__(512, 2) void gemm256(
    const uint16_t* __restrict__ A, size_t a_estride,
    const uint16_t* __restrict__ Bt,
    const float*    __restrict__ bias,
    uint16_t*       __restrict__ C,
    int M, int K) {
  __shared__ __attribute__((aligned(16))) char lds[131072];
  const int tid = threadIdx.x;
  const int bx  = blockIdx.x;
  const int e   = bx & 7;            // member -> XCD pinning
  const int t   = bx >> 3;
  const int mt  = t >> 2;            // nt inner: neighbors share A panel
  const int nt  = t & 3;
  const int NT  = K >> 6;            // K-tiles of 64
  const int HT  = NT * 4;            // total windows

  const uint16_t* Ae = A + (size_t)e * a_estride + (size_t)(mt * 256) * K;
  const uint16_t* Be = Bt + ((size_t)e * HID + nt * 256) * K;

  const int l  = tid & 63, wid = tid >> 6;
  const int wr = wid >> 2, wc = wid & 3;
  const int fr = l & 15, kq = l >> 4, f7 = fr & 7;

  // staging: thread covers line srow (128B), phys unit tid&7 -> logical su
  const int srow = tid >> 3;
  const int su   = (tid & 7) ^ (srow & 7);
  const uint16_t* sA0 = Ae + (size_t)srow * K + su * 8;
  const uint16_t* sB0 = Be + (size_t)srow * K + su * 8;
  char* const dst0 = lds + tid * 16;

  // read bases (within dbuf): +mi*2048 (+49152 if mi>=4), ^ (kh*64)
  const int rdA = wr * 8192 + fr * 128 + ((kq ^ f7) << 4);
  const int rdB = ((wc < 2) ? 16384 : 32768) + (wc & 1) * 8192 + fr * 128 + ((kq ^ f7) << 4);

  f32x4 acc[8][4];
  #pragma unroll
  for (int i = 0; i < 8; ++i)
    #pragma unroll
    for (int j = 0; j < 4; ++j) acc[i][j] = (f32x4)0.0f;

  auto STAGE = [&](int H) {
    const int tH = H >> 2, w = H & 3;
    char* dst = dst0 + ((tH & 1) << 16) + (w << 14);
    const size_t ko = (size_t)tH << 6;
    switch (w) {
      case 0: gload16(sA0 + ko, dst);
              gload16(sA0 + (size_t)128 * K + ko, dst + 8192); break;
      case 1: gload16(sB0 + ko, dst);
              gload16(sB0 + (size_t)64 * K + ko, dst + 8192); break;
      case 2: gload16(sB0 + (size_t)128 * K + ko, dst);
              gload16(sB0 + (size_t)192 * K + ko, dst + 8192); break;
      default: gload16(sA0 + (size_t)64 * K + ko, dst);
               gload16(sA0 + (size_t)192 * K + ko, dst + 8192); break;
    }
  };

  // prologue: windows 0..6 (tile0 full + tile1 w0-2); vmcnt(6) -> tile0 landed
  int H = 0;
  for (; H < 7; ++H) STAGE(H);
  WAIT_VM(6);
  BAR();

  bf16x8 af[4][2], bv[4][2];
  for (int kt = 0; kt < NT; ++kt) {
    const char* rb = lds + ((kt & 1) << 16);
    // ---- phase 0: read A-q0 (8) + B ni0-1 (4); MFMA mi0-3 x ni0-1 ----
    #pragma unroll
    for (int mi = 0; mi < 4; ++mi) {
      af[mi][0] = *(const bf16x8*)(rb + (rdA + mi * 2048));
      af[mi][1] = *(const bf16x8*)(rb + ((rdA + mi * 2048) ^ 64));
    }
    #pragma unroll
    for (int ni = 0; ni < 2; ++ni) {
      bv[ni][0] = *(const bf16x8*)(rb + (rdB + ni * 2048));
      bv[ni][1] = *(const bf16x8*)(rb + ((rdB + ni * 2048) ^ 64));
    }
    if (H < HT) STAGE(H++);
    BAR();
    __builtin_amdgcn_s_setprio(1);
    #pragma unroll
    for (int mi = 0; mi < 4; ++mi)
      #pragma unroll
      for (int ni = 0; ni < 2; ++ni) {
        acc[mi][ni] = MF(af[mi][0], bv[ni][0], acc[mi][ni]);
        acc[mi][ni] = MF(af[mi][1], bv[ni][1], acc[mi][ni]);
      }
    __builtin_amdgcn_s_setprio(0);
    BAR();
    // ---- phase 1: read B ni2-3 (4); MFMA mi0-3 x ni2-3 ----
    #pragma unroll
    for (int ni = 2; ni < 4; ++ni) {
      bv[ni][0] = *(const bf16x8*)(rb + (rdB + ni * 2048));
      bv[ni][1] = *(const bf16x8*)(rb + ((rdB + ni * 2048) ^ 64));
    }
    if (H < HT) STAGE(H++);
    BAR();
    __builtin_amdgcn_s_setprio(1);
    #pragma unroll
    for (int mi = 0; mi < 4; ++mi)
      #pragma unroll
      for (int ni = 2; ni < 4; ++ni) {
        acc[mi][ni] = MF(af[mi][0], bv[ni][0], acc[mi][ni]);
        acc[mi][ni] = MF(af[mi][1], bv[ni][1], acc[mi][ni]);
      }
    __builtin_amdgcn_s_setprio(0);
    BAR();
    // ---- phase 2: read A-q1 (8); MFMA mi4-7 x ni0-1 ----
    #pragma unroll
    for (int mi = 0; mi < 4; ++mi) {
      af[mi][0] = *(const bf16x8*)(rb + (rdA + 49152 + mi * 2048));
      af[mi][1] = *(const bf16x8*)(rb + ((rdA + 49152 + mi * 2048) ^ 64));
    }
    if (H < HT) STAGE(H++);
    BAR();
    __builtin_amdgcn_s_setprio(1);
    #pragma unroll
    for (int mi = 0; mi < 4; ++mi)
      #pragma unroll
      for (int ni = 0; ni < 2; ++ni) {
        acc[mi + 4][ni] = MF(af[mi][0], bv[ni][0], acc[mi + 4][ni]);
        acc[mi + 4][ni] = MF(af[mi][1], bv[ni][1], acc[mi + 4][ni]);
      }
    __builtin_amdgcn_s_setprio(0);
    BAR();
    // ---- phase 3: no reads; MFMA mi4-7 x ni2-3; counted vmcnt once per K-tile ----
    if (H < HT) STAGE(H++);
    BAR();
    __builtin_amdgcn_s_setprio(1);
    #pragma unroll
    for (int mi = 0; mi < 4; ++mi)
      #pragma unroll
      for (int ni = 2; ni < 4; ++ni) {
        acc[mi + 4][ni] = MF(af[mi][0], bv[ni][0], acc[mi + 4][ni]);
        acc[mi + 4][ni] = MF(af[mi][1], bv[ni][1], acc[mi + 4][ni]);
      }
    __builtin_amdgcn_s_setprio(0);
    if (kt < NT - 2)       WAIT_VM(6);
    else if (kt == NT - 2) WAIT_VM(0);
    BAR();
  }

  // epilogue: bias + direct bf16 store.  D map: col=l&15, row=(l>>4)*4+i [m89]
  const int col0 = nt * 256 + wc * 64 + fr;
  const int row0 = mt * 256 + wr * 128 + kq * 4;
  float bvv[4];
  #pragma unroll
  for (int ni = 0; ni < 4; ++ni) bvv[ni] = bias[(size_t)e * HID + col0 + ni * 16];
  #pragma unroll
  for (int mi = 0; mi < 8; ++mi) {
    #pragma unroll
    for (int i = 0; i < 4; ++i) {
      const int rg = row0 + mi * 16 + i;
      uint16_t* cp = C + ((size_t)e * M + rg) * HID + col0;
      #pragma unroll
      for (int ni = 0; ni < 4; ++ni)
        cp[ni * 16] = f2bf(acc[mi][ni][i] + bvv[ni]);
    }
  }
}

// ---------------- LayerNorm + ReLU, in place on bf16 [E*CB][HID] ----------------
__global__ __launch_bounds__(256) void ln_relu(uint16_t* __restrict__ h,
                                               const float* __restrict__ g,
                                               const float* __restrict__ be,
                                               int kshift) {        // e = row >> kshift
  const int wid = threadIdx.x >> 6, l = threadIdx.x & 63;
  const long row = (long)blockIdx.x * 4 + wid;
  const int e = (int)(row >> kshift);
  uint16_t* p = h + row * HID;

  u16x8 s0 = *(const u16x8*)(p + l * 8);
  u16x8 s1 = *(const u16x8*)(p + 512 + l * 8);
  float v[16];
  #pragma unroll
  for (int j = 0; j < 8; ++j) { v[j] = bf2f(s0[j]); v[8 + j] = bf2f(s1[j]); }

  float sum = 0.f, sq = 0.f;
  #pragma unroll
  for (int j = 0; j < 16; ++j) { sum += v[j]; sq += v[j] * v[j]; }
  #pragma unroll
  for (int m = 1; m < 64; m <<= 1) {
    sum += __shfl_xor(sum, m);
    sq  += __shfl_xor(sq, m);
  }
  const float mu  = sum * (1.0f / HID);
  const float var = sq * (1.0f / HID) - mu * mu;
  const float rs  = rsqrtf(var + LN_EPS);

  const float* gp = g  + (size_t)e * HID;
  const float* bp = be + (size_t)e * HID;
  u16x8 o0, o1;
  #pragma unroll
  for (int j = 0; j < 8; ++j) {
    const int c0 = l * 8 + j, c1 = 512 + l * 8 + j;
    float x0 = (v[j]     - mu) * rs * gp[c0] + bp[c0];
    float x1 = (v[8 + j] - mu) * rs * gp[c1] + bp[c1];
    o0[j] = f2bf(fmaxf(x0, 0.f));
    o1[j] = f2bf(fmaxf(x1, 0.f));
  }
  *(u16x8*)(p + l * 8) = o0;
  *(u16x8*)(p + 512 + l * 8) = o1;
}

// ------- fused LN2 + ReLU + head dot + min: reads pre-LN h2, writes q/qs only -------
__global__ __launch_bounds__(256) void ln_head(const uint16_t* __restrict__ h,
                                               const float* __restrict__ g,
                                               const float* __restrict__ be,
                                               const float* __restrict__ W3,
                                               const float* __restrict__ b3,
                                               float* __restrict__ out,
                                               int b0, int CB) {
  __shared__ float qsh[EN];
  const int wv = threadIdx.x >> 6, l = threadIdx.x & 63;
  const long b = blockIdx.x;
  #pragma unroll
  for (int ee = 0; ee < 2; ++ee) {
    const int e = wv + ee * 4;
    const uint16_t* p = h + ((size_t)e * CB + b) * HID;
    u16x8 s0 = *(const u16x8*)(p + l * 8);
    u16x8 s1 = *(const u16x8*)(p + 512 + l * 8);
    float v[16];
    #pragma unroll
    for (int j = 0; j < 8; ++j) { v[j] = bf2f(s0[j]); v[8 + j] = bf2f(s1[j]); }
    float sum = 0.f, sq = 0.f;
    #pragma unroll
    for (int j = 0; j < 16; ++j) { sum += v[j]; sq += v[j] * v[j]; }
    #pragma unroll
    for (int m = 1; m < 64; m <<= 1) {
      sum += __shfl_xor(sum, m);
      sq  += __shfl_xor(sq, m);
    }
    const float mu  = sum * (1.0f / HID);
    const float var = sq * (1.0f / HID) - mu * mu;
    const float rs  = rsqrtf(var + LN_EPS);
    const float* gp = g  + (size_t)e * HID;
    const float* bp = be + (size_t)e * HID;
    const float* w  = W3 + (size_t)e * HID;
    float dot = 0.f;
    #pragma unroll
    for (int j = 0; j < 8; ++j) {
      const int c0 = l * 8 + j, c1 = 512 + l * 8 + j;
      float x0 = fmaxf((v[j]     - mu) * rs * gp[c0] + bp[c0], 0.f);
      float x1 = fmaxf((v[8 + j] - mu) * rs * gp[c1] + bp[c1], 0.f);
      dot += x0 * w[c0] + x1 * w[c1];
    }
    #pragma unroll
    for (int m = 1; m < 64; m <<= 1) dot += __shfl_xor(dot, m);
    if (l == 0) {
      const float qe = dot + b3[e];
      qsh[e] = qe;
      out[BATCH + (size_t)e * BATCH + b0 + b] = qe;   // qs
    }
  }
  __syncthreads();
  if (threadIdx.x == 0) {
    float m = qsh[0];
    #pragma unroll
    for (int i = 1; i < EN; ++i) m = fminf(m, qsh[i]);
    out[b0 + b] = m;                                   // q
  }
}

extern "C" void kernel_launch(void* const* d_in, const int* in_sizes, int n_in,
                              void* d_out, int out_size, void* d_ws, size_t ws_size,
                              hipStream_t stream) {
  const float* x   = (const float*)d_in[0];
  const float* W1  = (const float*)d_in[1];
  const float* b1  = (const float*)d_in[2];
  const float* g1  = (const float*)d_in[3];
  const float* be1 = (const float*)d_in[4];
  const float* W2  = (const float*)d_in[5];
  const float* b2  = (const float*)d_in[6];
  const float* g2  = (const float*)d_in[7];
  const float* be2 = (const float*)d_in[8];
  const float* W3  = (const float*)d_in[9];
  const float* b3  = (const float*)d_in[10];
  float* out = (float*)d_out;

  // ---- fixed workspace region: converted inputs (40 MB) ----
  char* ws = (char*)d_ws;
  uint16_t* xb  = (uint16_t*)ws; ws += (size_t)BATCH * DIN * 2;      // 16 MB
  uint16_t* w1t = (uint16_t*)ws; ws += (size_t)EN * DIN * HID * 2;   // 8 MB
  uint16_t* w2t = (uint16_t*)ws; ws += (size_t)EN * HID * HID * 2;   // 16 MB
  size_t fixed = (size_t)(ws - (char*)d_ws);

  // ---- batch-chunk size CB (power of 2, >=256) so h1+h2 fit in workspace ----
  size_t avail = (ws_size > fixed) ? (ws_size - fixed) : 0;
  const size_t per_row = 2ULL * EN * HID * 2ULL;   // h1+h2 bytes per batch row
  int CB = BATCH;
  while (CB > 256 && (size_t)CB * per_row > avail) CB >>= 1;
  const int nchunks = BATCH / CB;
  const int kshift = __builtin_ctz(CB);

  uint16_t* h1 = (uint16_t*)ws; ws += (size_t)EN * CB * HID * 2;
  uint16_t* h2 = (uint16_t*)ws;

  // ---- one-time conversions ----
  cvt_bf16<<<(BATCH * DIN / 4 + 255) / 256, 256, 0, stream>>>(x, xb, (long)BATCH * DIN);
  transpose_cvt<<<dim3(HID / 32, DIN / 32, EN), 256, 0, stream>>>(W1, w1t, DIN, HID);
  transpose_cvt<<<dim3(HID / 32, HID / 32, EN), 256, 0, stream>>>(W2, w2t, HID, HID);

  const int gblocks = (CB / 256) * (HID / 256) * EN;

  for (int c = 0; c < nchunks; ++c) {
    const int b0 = c * CB;
    gemm256<<<gblocks, 512, 0, stream>>>(xb + (size_t)b0 * DIN, (size_t)0,
                                         w1t, b1, h1, CB, DIN);
    ln_relu<<<(EN * CB) / 4, 256, 0, stream>>>(h1, g1, be1, kshift);
    gemm256<<<gblocks, 512, 0, stream>>>(h1, (size_t)CB * HID,
                                         w2t, b2, h2, CB, HID);
    ln_head<<<CB, 256, 0, stream>>>(h2, g2, be2, W3, b3, out, b0, CB);
  }
}

// Round 8
// 682.999 us; speedup vs baseline: 1.0005x; 1.0005x over previous
//
#include <hip/hip_runtime.h>
#include <hip/hip_bf16.h>
#include <stdint.h>

#define EN    8
#define DIN   512
#define HID   1024
#define BATCH 16384
#define LN_EPS 1e-5f

typedef __bf16   bf16x8 __attribute__((ext_vector_type(8)));
typedef float    f32x4  __attribute__((ext_vector_type(4)));
typedef uint16_t u16x8  __attribute__((ext_vector_type(8)));
typedef uint16_t u16x4  __attribute__((ext_vector_type(4)));
typedef float    fl4    __attribute__((ext_vector_type(4)));

__device__ __forceinline__ uint16_t f2bf(float f) {
  uint32_t x = __builtin_bit_cast(uint32_t, f);
  uint32_t r = (x + 0x7fffu + ((x >> 16) & 1u)) >> 16;  // RNE
  return (uint16_t)r;
}
__device__ __forceinline__ float bf2f(uint16_t u) {
  return __builtin_bit_cast(float, (uint32_t)u << 16);
}

__device__ __forceinline__ void gload16(const uint16_t* g, char* lds_d) {
  __builtin_amdgcn_global_load_lds(
      (const __attribute__((address_space(1))) uint32_t*)g,
      (__attribute__((address_space(3))) uint32_t*)lds_d, 16, 0, 0);
}

__device__ __forceinline__ f32x4 MF(bf16x8 a, bf16x8 b, f32x4 c) {
  return __builtin_amdgcn_mfma_f32_16x16x32_bf16(a, b, c, 0, 0, 0);
}

#define SB0() __builtin_amdgcn_sched_barrier(0)
__device__ __forceinline__ void BARRIER() { __builtin_amdgcn_s_barrier(); }

// ---------------- conversion: fp32 -> bf16 ----------------
__global__ __launch_bounds__(256) void cvt_bf16(const float* __restrict__ src,
                                                uint16_t* __restrict__ dst, long n) {
  long i = ((long)blockIdx.x * 256 + threadIdx.x) * 4;
  if (i >= n) return;
  fl4 v = *(const fl4*)(src + i);
  u16x4 o;
  #pragma unroll
  for (int j = 0; j < 4; ++j) o[j] = f2bf(v[j]);
  *(u16x4*)(dst + i) = o;
}

// ---------------- transpose + convert: [E][R][C] fp32 -> [E][C][R] bf16 ----------------
__global__ __launch_bounds__(256) void transpose_cvt(const float* __restrict__ src,
                                                     uint16_t* __restrict__ dst,
                                                     int R, int C) {
  __shared__ float tile[32][33];
  const int e = blockIdx.z;
  const int c0 = blockIdx.x * 32;
  const int r0 = blockIdx.y * 32;
  const int tx = threadIdx.x & 31, ty = threadIdx.x >> 5;
  const float* s = src + (size_t)e * R * C;
  uint16_t*    d = dst + (size_t)e * R * C;
  #pragma unroll
  for (int i = 0; i < 32; i += 8)
    tile[ty + i][tx] = s[(size_t)(r0 + ty + i) * C + (c0 + tx)];
  __syncthreads();
  #pragma unroll
  for (int i = 0; i < 32; i += 8)
    d[(size_t)(c0 + ty + i) * R + (r0 + tx)] = f2bf(tile[tx][ty + i]);
}

// ========== 256x256 GEMM, 8 sub-phases/K-tile, one-phase-lookahead reads ==========
// C[e][M][HID] = A[e][M][K] * Bt[e][HID][K]^T + bias.  512 thr = 8 waves (2M x 4N),
// wave tile 128x64, BK=64.  LDS 128 KiB = 2 dbuf x 4 windows x 16 KiB:
//   [w0: A rows{0-63,128-191} | w1: B cols 0-127 | w2: B cols 128-255 | w3: A rows{64-127,192-255}]
// 128B rows, 16B unit u at phys u ^ (row&7) (proven 0-conflict).  One window staged per
// EVEN phase (window H = P/2 + 7).  Reads issued >=1 phase before use; frag register ring
// reuses each set right after its last consumer.  vmcnt(8) after stage, before barrier
// (publication): landed floor covers every read's window (ledger verified per-phase).
__global__ __launch_bounds__(512, 2) void gemm256(
    const uint16_t* __restrict__ A, size_t a_estride,
    const uint16_t* __restrict__ Bt,
    const float*    __restrict__ bias,
    uint16_t*       __restrict__ C,
    int M, int K) {
  __shared__ __attribute__((aligned(16))) char lds[131072];
  const int tid = threadIdx.x;
  const int bx  = blockIdx.x;
  const int e   = bx & 7;            // member -> XCD pinning
  const int t   = bx >> 3;
  const int mt  = t >> 2;            // nt inner: neighbors share A panel
  const int nt  = t & 3;
  const int NT  = K >> 6;            // K-tiles of 64
  const int HT  = NT * 4;            // total windows

  const uint16_t* Ae = A + (size_t)e * a_estride + (size_t)(mt * 256) * K;
  const uint16_t* Be = Bt + ((size_t)e * HID + nt * 256) * K;

  const int l  = tid & 63, wid = tid >> 6;
  const int wr = wid >> 2, wc = wid & 3;
  const int fr = l & 15, kq = l >> 4, f7 = fr & 7;

  const int srow = tid >> 3;
  const int su   = (tid & 7) ^ (srow & 7);
  const uint16_t* sA0 = Ae + (size_t)srow * K + su * 8;
  const uint16_t* sB0 = Be + (size_t)srow * K + su * 8;
  char* const dst0 = lds + tid * 16;

  const int rdA = wr * 8192 + fr * 128 + ((kq ^ f7) << 4);
  const int rdB = ((wc < 2) ? 16384 : 32768) + (wc & 1) * 8192 + fr * 128 + ((kq ^ f7) << 4);

  f32x4 acc[8][4];
  #pragma unroll
  for (int i = 0; i < 8; ++i)
    #pragma unroll
    for (int j = 0; j < 4; ++j) acc[i][j] = (f32x4)0.0f;

  auto STAGE = [&](int H) {
    const int tH = H >> 2, w = H & 3;
    char* dst = dst0 + ((tH & 1) << 16) + (w << 14);
    const size_t ko = (size_t)tH << 6;
    switch (w) {
      case 0: gload16(sA0 + ko, dst);
              gload16(sA0 + (size_t)128 * K + ko, dst + 8192); break;
      case 1: gload16(sB0 + ko, dst);
              gload16(sB0 + (size_t)64 * K + ko, dst + 8192); break;
      case 2: gload16(sB0 + (size_t)128 * K + ko, dst);
              gload16(sB0 + (size_t)192 * K + ko, dst + 8192); break;
      default: gload16(sA0 + (size_t)64 * K + ko, dst);
               gload16(sA0 + (size_t)192 * K + ko, dst + 8192); break;
    }
  };

  // prologue: windows 0..6; vmcnt(8) -> windows 0..2 landed (w0,w1,w2: preload needs)
  int H = 0;
  for (; H < 7; ++H) STAGE(H);
  asm volatile("s_waitcnt vmcnt(8)");
  SB0();
  BARRIER();
  SB0();

  // frag ring: a0 = Aq0 cur-kh set, a0x = Aq0 other-kh, a1 = Aq1 (kh-shared),
  // b01/b23 = B ni{0,1}/{2,3} (kh-shared).  16 x b128 total.
  bf16x8 a0[4], a0x[4], a1[4], b01[2], b23[2];
  {  // preload tile0: a0 <- Aq0 kh0, b01 <- B01 kh0
    const char* rb = lds;
    #pragma unroll
    for (int mi = 0; mi < 4; ++mi) a0[mi] = *(const bf16x8*)(rb + (rdA + mi * 2048));
    #pragma unroll
    for (int ni = 0; ni < 2; ++ni) b01[ni] = *(const bf16x8*)(rb + (rdB + ni * 2048));
  }

  for (int kt = 0; kt < NT; ++kt) {
    const char* rb  = lds + ((kt & 1) << 16);
    const char* rbn = lds + (((kt + 1) & 1) << 16);
    const bool stg = true;
    // per-phase: SB0 | reads(for later phases) | STAGE(even) | MFMA(8) | vmcnt | SB0 | BAR
    #define PHASE_SYNC(P_EVEN)                                        \
      do {                                                            \
        if (kt < NT - 2) { asm volatile("s_waitcnt vmcnt(8)"); }      \
        SB0();                                                        \
        BARRIER();                                                    \
        SB0();                                                        \
      } while (0)

    // ---- p0: reads b23(kh0); stage; MFMA Q0h0 = a0 x b01 -> acc[0..3][0,1] ----
    #pragma unroll
    for (int ni = 0; ni < 2; ++ni) b23[ni] = *(const bf16x8*)(rb + (rdB + (ni + 2) * 2048));
    if (H < HT) STAGE(H++);
    __builtin_amdgcn_s_setprio(1);
    #pragma unroll
    for (int mi = 0; mi < 4; ++mi)
      #pragma unroll
      for (int ni = 0; ni < 2; ++ni) acc[mi][ni] = MF(a0[mi], b01[ni], acc[mi][ni]);
    __builtin_amdgcn_s_setprio(0);
    if (kt < NT - 2) { asm volatile("s_waitcnt vmcnt(8)"); }
    else if (kt == NT - 2) { asm volatile("s_waitcnt vmcnt(0)"); }
    SB0(); BARRIER(); SB0();

    // ---- p1: reads a1(kh0) + a0x(kh1); MFMA Q1h0 = a0 x b23 -> acc[0..3][2,3] ----
    #pragma unroll
    for (int mi = 0; mi < 4; ++mi) a1[mi] = *(const bf16x8*)(rb + (rdA + 49152 + mi * 2048));
    #pragma unroll
    for (int mi = 0; mi < 4; ++mi) a0x[mi] = *(const bf16x8*)(rb + ((rdA + mi * 2048) ^ 64));
    __builtin_amdgcn_s_setprio(1);
    #pragma unroll
    for (int mi = 0; mi < 4; ++mi)
      #pragma unroll
      for (int ni = 2; ni < 4; ++ni) acc[mi][ni] = MF(a0[mi], b23[ni - 2], acc[mi][ni]);
    __builtin_amdgcn_s_setprio(0);
    if (kt < NT - 2) { asm volatile("s_waitcnt vmcnt(8)"); }
    SB0(); BARRIER(); SB0();

    // ---- p2: no reads; stage; MFMA Q2h0 = a1 x b01 -> acc[4..7][0,1] ----
    if (H < HT) STAGE(H++);
    __builtin_amdgcn_s_setprio(1);
    #pragma unroll
    for (int mi = 0; mi < 4; ++mi)
      #pragma unroll
      for (int ni = 0; ni < 2; ++ni) acc[mi + 4][ni] = MF(a1[mi], b01[ni], acc[mi + 4][ni]);
    __builtin_amdgcn_s_setprio(0);
    if (kt < NT - 2) { asm volatile("s_waitcnt vmcnt(8)"); }
    SB0(); BARRIER(); SB0();

    // ---- p3: reads b01(kh1); MFMA Q3h0 = a1 x b23 -> acc[4..7][2,3] ----
    #pragma unroll
    for (int ni = 0; ni < 2; ++ni) b01[ni] = *(const bf16x8*)(rb + ((rdB + ni * 2048) ^ 64));
    __builtin_amdgcn_s_setprio(1);
    #pragma unroll
    for (int mi = 0; mi < 4; ++mi)
      #pragma unroll
      for (int ni = 2; ni < 4; ++ni) acc[mi + 4][ni] = MF(a1[mi], b23[ni - 2], acc[mi + 4][ni]);
    __builtin_amdgcn_s_setprio(0);
    if (kt < NT - 2) { asm volatile("s_waitcnt vmcnt(8)"); }
    SB0(); BARRIER(); SB0();

    // ---- p4: reads b23(kh1); stage; MFMA Q0h1 = a0x x b01 -> acc[0..3][0,1] ----
    #pragma unroll
    for (int ni = 0; ni < 2; ++ni) b23[ni] = *(const bf16x8*)(rb + ((rdB + (ni + 2) * 2048) ^ 64));
    if (H < HT) STAGE(H++);
    __builtin_amdgcn_s_setprio(1);
    #pragma unroll
    for (int mi = 0; mi < 4; ++mi)
      #pragma unroll
      for (int ni = 0; ni < 2; ++ni) acc[mi][ni] = MF(a0x[mi], b01[ni], acc[mi][ni]);
    __builtin_amdgcn_s_setprio(0);
    if (kt < NT - 2) { asm volatile("s_waitcnt vmcnt(8)"); }
    SB0(); BARRIER(); SB0();

    // ---- p5: reads a1(kh1); MFMA Q1h1 = a0x x b23 -> acc[0..3][2,3] ----
    #pragma unroll
    for (int mi = 0; mi < 4; ++mi) a1[mi] = *(const bf16x8*)(rb + ((rdA + 49152 + mi * 2048) ^ 64));
    __builtin_amdgcn_s_setprio(1);
    #pragma unroll
    for (int mi = 0; mi < 4; ++mi)
      #pragma unroll
      for (int ni = 2; ni < 4; ++ni) acc[mi][ni] = MF(a0x[mi], b23[ni - 2], acc[mi][ni]);
    __builtin_amdgcn_s_setprio(0);
    if (kt < NT - 2) { asm volatile("s_waitcnt vmcnt(8)"); }
    SB0(); BARRIER(); SB0();

    // ---- p6: reads next-tile a0 (kh0, NXT buf); stage; MFMA Q2h1 = a1 x b01 ----
    if (kt + 1 < NT) {
      #pragma unroll
      for (int mi = 0; mi < 4; ++mi) a0[mi] = *(const bf16x8*)(rbn + (rdA + mi * 2048));
    }
    if (H < HT) STAGE(H++);
    __builtin_amdgcn_s_setprio(1);
    #pragma unroll
    for (int mi = 0; mi < 4; ++mi)
      #pragma unroll
      for (int ni = 0; ni < 2; ++ni) acc[mi + 4][ni] = MF(a1[mi], b01[ni], acc[mi + 4][ni]);
    __builtin_amdgcn_s_setprio(0);
    if (kt < NT - 2) { asm volatile("s_waitcnt vmcnt(8)"); }
    SB0(); BARRIER(); SB0();

    // ---- p7: reads next-tile b01 (kh0, NXT buf); MFMA Q3h1 = a1 x b23 ----
    if (kt + 1 < NT) {
      #pragma unroll
      for (int ni = 0; ni < 2; ++ni) b01[ni] = *(const bf16x8*)(rbn + (rdB + ni * 2048));
    }
    __builtin_amdgcn_s_setprio(1);
    #pragma unroll
    for (int mi = 0; mi < 4; ++mi)
      #pragma unroll
      for (int ni = 2; ni < 4; ++ni) acc[mi + 4][ni] = MF(a1[mi], b23[ni - 2], acc[mi + 4][ni]);
    __builtin_amdgcn_s_setprio(0);
    if (kt < NT - 2) { asm volatile("s_waitcnt vmcnt(8)"); }
    SB0(); BARRIER(); SB0();
    (void)stg;
    #undef PHASE_SYNC
  }

  // epilogue: bias + direct bf16 store.  D map: col=l&15, row=(l>>4)*4+i [m89]
  const int col0 = nt * 256 + wc * 64 + fr;
  const int row0 = mt * 256 + wr * 128 + kq * 4;
  float bvv[4];
  #pragma unroll
  for (int ni = 0; ni < 4; ++ni) bvv[ni] = bias[(size_t)e * HID + col0 + ni * 16];
  #pragma unroll
  for (int mi = 0; mi < 8; ++mi) {
    #pragma unroll
    for (int i = 0; i < 4; ++i) {
      const int rg = row0 + mi * 16 + i;
      uint16_t* cp = C + ((size_t)e * M + rg) * HID + col0;
      #pragma unroll
      for (int ni = 0; ni < 4; ++ni)
        cp[ni * 16] = f2bf(acc[mi][ni][i] + bvv[ni]);
    }
  }
}

// ---------------- LayerNorm + ReLU, in place on bf16 [E*CB][HID] ----------------
__global__ __launch_bounds__(256) void ln_relu(uint16_t* __restrict__ h,
                                               const float* __restrict__ g,
                                               const float* __restrict__ be,
                                               int kshift) {        // e = row >> kshift
  const int wid = threadIdx.x >> 6, l = threadIdx.x & 63;
  const long row = (long)blockIdx.x * 4 + wid;
  const int e = (int)(row >> kshift);
  uint16_t* p = h + row * HID;

  u16x8 s0 = *(const u16x8*)(p + l * 8);
  u16x8 s1 = *(const u16x8*)(p + 512 + l * 8);
  float v[16];
  #pragma unroll
  for (int j = 0; j < 8; ++j) { v[j] = bf2f(s0[j]); v[8 + j] = bf2f(s1[j]); }

  float sum = 0.f, sq = 0.f;
  #pragma unroll
  for (int j = 0; j < 16; ++j) { sum += v[j]; sq += v[j] * v[j]; }
  #pragma unroll
  for (int m = 1; m < 64; m <<= 1) {
    sum += __shfl_xor(sum, m);
    sq  += __shfl_xor(sq, m);
  }
  const float mu  = sum * (1.0f / HID);
  const float var = sq * (1.0f / HID) - mu * mu;
  const float rs  = rsqrtf(var + LN_EPS);

  const float* gp = g  + (size_t)e * HID;
  const float* bp = be + (size_t)e * HID;
  u16x8 o0, o1;
  #pragma unroll
  for (int j = 0; j < 8; ++j) {
    const int c0 = l * 8 + j, c1 = 512 + l * 8 + j;
    float x0 = (v[j]     - mu) * rs * gp[c0] + bp[c0];
    float x1 = (v[8 + j] - mu) * rs * gp[c1] + bp[c1];
    o0[j] = f2bf(fmaxf(x0, 0.f));
    o1[j] = f2bf(fmaxf(x1, 0.f));
  }
  *(u16x8*)(p + l * 8) = o0;
  *(u16x8*)(p + 512 + l * 8) = o1;
}

// ------- fused LN2 + ReLU + head dot + min: reads pre-LN h2, writes q/qs only -------
__global__ __launch_bounds__(256) void ln_head(const uint16_t* __restrict__ h,
                                               const float* __restrict__ g,
                                               const float* __restrict__ be,
                                               const float* __restrict__ W3,
                                               const float* __restrict__ b3,
                                               float* __restrict__ out,
                                               int b0, int CB) {
  __shared__ float qsh[EN];
  const int wv = threadIdx.x >> 6, l = threadIdx.x & 63;
  const long b = blockIdx.x;
  #pragma unroll
  for (int ee = 0; ee < 2; ++ee) {
    const int e = wv + ee * 4;
    const uint16_t* p = h + ((size_t)e * CB + b) * HID;
    u16x8 s0 = *(const u16x8*)(p + l * 8);
    u16x8 s1 = *(const u16x8*)(p + 512 + l * 8);
    float v[16];
    #pragma unroll
    for (int j = 0; j < 8; ++j) { v[j] = bf2f(s0[j]); v[8 + j] = bf2f(s1[j]); }
    float sum = 0.f, sq = 0.f;
    #pragma unroll
    for (int j = 0; j < 16; ++j) { sum += v[j]; sq += v[j] * v[j]; }
    #pragma unroll
    for (int m = 1; m < 64; m <<= 1) {
      sum += __shfl_xor(sum, m);
      sq  += __shfl_xor(sq, m);
    }
    const float mu  = sum * (1.0f / HID);
    const float var = sq * (1.0f / HID) - mu * mu;
    const float rs  = rsqrtf(var + LN_EPS);
    const float* gp = g  + (size_t)e * HID;
    const float* bp = be + (size_t)e * HID;
    const float* w  = W3 + (size_t)e * HID;
    float dot = 0.f;
    #pragma unroll
    for (int j = 0; j < 8; ++j) {
      const int c0 = l * 8 + j, c1 = 512 + l * 8 + j;
      float x0 = fmaxf((v[j]     - mu) * rs * gp[c0] + bp[c0], 0.f);
      float x1 = fmaxf((v[8 + j] - mu) * rs * gp[c1] + bp[c1], 0.f);
      dot += x0 * w[c0] + x1 * w[c1];
    }
    #pragma unroll
    for (int m = 1; m < 64; m <<= 1) dot += __shfl_xor(dot, m);
    if (l == 0) {
      const float qe = dot + b3[e];
      qsh[e] = qe;
      out[BATCH + (size_t)e * BATCH + b0 + b] = qe;   // qs
    }
  }
  __syncthreads();
  if (threadIdx.x == 0) {
    float m = qsh[0];
    #pragma unroll
    for (int i = 1; i < EN; ++i) m = fminf(m, qsh[i]);
    out[b0 + b] = m;                                   // q
  }
}

extern "C" void kernel_launch(void* const* d_in, const int* in_sizes, int n_in,
                              void* d_out, int out_size, void* d_ws, size_t ws_size,
                              hipStream_t stream) {
  const float* x   = (const float*)d_in[0];
  const float* W1  = (const float*)d_in[1];
  const float* b1  = (const float*)d_in[2];
  const float* g1  = (const float*)d_in[3];
  const float* be1 = (const float*)d_in[4];
  const float* W2  = (const float*)d_in[5];
  const float* b2  = (const float*)d_in[6];
  const float* g2  = (const float*)d_in[7];
  const float* be2 = (const float*)d_in[8];
  const float* W3  = (const float*)d_in[9];
  const float* b3  = (const float*)d_in[10];
  float* out = (float*)d_out;

  // ---- fixed workspace region: converted inputs (40 MB) ----
  char* ws = (char*)d_ws;
  uint16_t* xb  = (uint16_t*)ws; ws += (size_t)BATCH * DIN * 2;      // 16 MB
  uint16_t* w1t = (uint16_t*)ws; ws += (size_t)EN * DIN * HID * 2;   // 8 MB
  uint16_t* w2t = (uint16_t*)ws; ws += (size_t)EN * HID * HID * 2;   // 16 MB
  size_t fixed = (size_t)(ws - (char*)d_ws);

  // ---- batch-chunk size CB (power of 2, >=256) so h1+h2 fit in workspace ----
  size_t avail = (ws_size > fixed) ? (ws_size - fixed) : 0;
  const size_t per_row = 2ULL * EN * HID * 2ULL;   // h1+h2 bytes per batch row
  int CB = BATCH;
  while (CB > 256 && (size_t)CB * per_row > avail) CB >>= 1;
  const int nchunks = BATCH / CB;
  const int kshift = __builtin_ctz(CB);

  uint16_t* h1 = (uint16_t*)ws; ws += (size_t)EN * CB * HID * 2;
  uint16_t* h2 = (uint16_t*)ws;

  // ---- one-time conversions ----
  cvt_bf16<<<(BATCH * DIN / 4 + 255) / 256, 256, 0, stream>>>(x, xb, (long)BATCH * DIN);
  transpose_cvt<<<dim3(HID / 32, DIN / 32, EN), 256, 0, stream>>>(W1, w1t, DIN, HID);
  transpose_cvt<<<dim3(HID / 32, HID / 32, EN), 256, 0, stream>>>(W2, w2t, HID, HID);

  const int gblocks = (CB / 256) * (HID / 256) * EN;

  for (int c = 0; c < nchunks; ++c) {
    const int b0 = c * CB;
    gemm256<<<gblocks, 512, 0, stream>>>(xb + (size_t)b0 * DIN, (size_t)0,
                                         w1t, b1, h1, CB, DIN);
    ln_relu<<<(EN * CB) / 4, 256, 0, stream>>>(h1, g1, be1, kshift);
    gemm256<<<gblocks, 512, 0, stream>>>(h1, (size_t)CB * HID,
                                         w2t, b2, h2, CB, HID);
    ln_head<<<CB, 256, 0, stream>>>(h2, g2, be2, W3, b3, out, b0, CB);
  }
}

// Round 9
// 659.922 us; speedup vs baseline: 1.0355x; 1.0350x over previous
//
#include <hip/hip_runtime.h>
#include <hip/hip_bf16.h>
#include <stdint.h>

#define EN    8
#define DIN   512
#define HID   1024
#define BATCH 16384
#define LN_EPS 1e-5f

typedef __bf16   bf16x8 __attribute__((ext_vector_type(8)));
typedef float    f32x4  __attribute__((ext_vector_type(4)));
typedef uint16_t u16x8  __attribute__((ext_vector_type(8)));
typedef uint16_t u16x4  __attribute__((ext_vector_type(4)));
typedef float    fl4    __attribute__((ext_vector_type(4)));

__device__ __forceinline__ uint16_t f2bf(float f) {
  uint32_t x = __builtin_bit_cast(uint32_t, f);
  uint32_t r = (x + 0x7fffu + ((x >> 16) & 1u)) >> 16;  // RNE
  return (uint16_t)r;
}
__device__ __forceinline__ float bf2f(uint16_t u) {
  return __builtin_bit_cast(float, (uint32_t)u << 16);
}

__device__ __forceinline__ void gload16(const uint16_t* g, char* lds_d) {
  __builtin_amdgcn_global_load_lds(
      (const __attribute__((address_space(1))) uint32_t*)g,
      (__attribute__((address_space(3))) uint32_t*)lds_d, 16, 0, 0);
}

__device__ __forceinline__ f32x4 MF(bf16x8 a, bf16x8 b, f32x4 c) {
  return __builtin_amdgcn_mfma_f32_16x16x32_bf16(a, b, c, 0, 0, 0);
}

#define SB0() __builtin_amdgcn_sched_barrier(0)

// ---------------- conversion: fp32 -> bf16 ----------------
__global__ __launch_bounds__(256) void cvt_bf16(const float* __restrict__ src,
                                                uint16_t* __restrict__ dst, long n) {
  long i = ((long)blockIdx.x * 256 + threadIdx.x) * 4;
  if (i >= n) return;
  fl4 v = *(const fl4*)(src + i);
  u16x4 o;
  #pragma unroll
  for (int j = 0; j < 4; ++j) o[j] = f2bf(v[j]);
  *(u16x4*)(dst + i) = o;
}

// ---------------- transpose + convert: [E][R][C] fp32 -> [E][C][R] bf16 ----------------
__global__ __launch_bounds__(256) void transpose_cvt(const float* __restrict__ src,
                                                     uint16_t* __restrict__ dst,
                                                     int R, int C) {
  __shared__ float tile[32][33];
  const int e = blockIdx.z;
  const int c0 = blockIdx.x * 32;
  const int r0 = blockIdx.y * 32;
  const int tx = threadIdx.x & 31, ty = threadIdx.x >> 5;
  const float* s = src + (size_t)e * R * C;
  uint16_t*    d = dst + (size_t)e * R * C;
  #pragma unroll
  for (int i = 0; i < 32; i += 8)
    tile[ty + i][tx] = s[(size_t)(r0 + ty + i) * C + (c0 + tx)];
  __syncthreads();
  #pragma unroll
  for (int i = 0; i < 32; i += 8)
    d[(size_t)(c0 + ty + i) * R + (r0 + tx)] = f2bf(tile[tx][ty + i]);
}

// ====== 256x256 GEMM, 4 waves, 128x128 wave tile, register-dbuf fragments ======
// C[e][M][HID] = A[e][M][K] * Bt[e][HID][K]^T + bias.  256 thr = 4 waves (2M x 2N).
// BK=64.  LDS 128 KiB = 2 dbuf x (A 256x128B + B 256x128B).  128B rows, 16B unit u
// at phys u ^ (row&7) (proven 0-conflict).  Per kt: halved LDS-read traffic
// (4 waves x 32 b128 = 128 KB) < MFMA work (2483 cyc) -> MFMA-bound with overlap.
// In-order-issue hiding: kh1 frag reads precede kh0 MFMA bursts; stage(kt+1)
// issues at kt top, vmcnt(0) ~2500 cyc later; 1 barrier/kt.
__global__ __launch_bounds__(256, 1) void gemm4w(
    const uint16_t* __restrict__ A, size_t a_estride,
    const uint16_t* __restrict__ Bt,
    const float*    __restrict__ bias,
    uint16_t*       __restrict__ C,
    int M, int K) {
  __shared__ __attribute__((aligned(16))) char lds[131072];
  const int tid = threadIdx.x;
  const int bx  = blockIdx.x;
  const int e   = bx & 7;            // member -> XCD pinning
  const int t   = bx >> 3;
  const int mt  = t >> 2;            // nt inner: neighbors share A panel
  const int nt  = t & 3;
  const int NT  = K >> 6;            // K-tiles of 64

  const uint16_t* Ae = A + (size_t)e * a_estride + (size_t)(mt * 256) * K;
  const uint16_t* Be = Bt + ((size_t)e * HID + nt * 256) * K;

  const int l  = tid & 63, wid = tid >> 6;
  const int wr = wid >> 1, wc = wid & 1;        // 2 x 2 waves, tile 128x128
  const int fr = l & 15, kq = l >> 4, f7 = fr & 7;

  // staging: lane covers row (wid*8 + l>>3) (+j*32), phys unit l&7, logical su
  const int r8 = l >> 3;
  const int su = (l & 7) ^ r8;
  const uint16_t* pA = Ae + (size_t)(wid * 8 + r8) * K + su * 8;
  const uint16_t* pB = Be + (size_t)(wid * 8 + r8) * K + su * 8;
  char* const dst0 = lds + tid * 16;            // dst = buf + j*4096 (+32768 for B)

  // frag read byte offsets (within dbuf): +mi*2048; kh1 = ^64
  const int rdA0 = (wr * 128 + fr) * 128 + ((kq ^ f7) << 4);
  const int rdB0 = 32768 + (wc * 128 + fr) * 128 + ((kq ^ f7) << 4);

  f32x4 acc[8][8];
  #pragma unroll
  for (int i = 0; i < 8; ++i)
    #pragma unroll
    for (int j = 0; j < 8; ++j) acc[i][j] = (f32x4)0.0f;

  auto STAGE = [&](int kt) {
    char* db = dst0 + ((kt & 1) << 16);
    const uint16_t* sa = pA + kt * 64;
    const uint16_t* sb = pB + kt * 64;
    #pragma unroll
    for (int j = 0; j < 8; ++j) gload16(sa + (size_t)(j * 32) * K, db + j * 4096);
    #pragma unroll
    for (int j = 0; j < 8; ++j) gload16(sb + (size_t)(j * 32) * K, db + 32768 + j * 4096);
  };

  // prologue
  STAGE(0);
  asm volatile("s_waitcnt vmcnt(0)");
  SB0();
  __builtin_amdgcn_s_barrier();
  SB0();

  bf16x8 a0[8], b0[8], a1[8], b1[8];
  {
    const char* rb = lds;
    #pragma unroll
    for (int i = 0; i < 8; ++i) {
      a0[i] = *(const bf16x8*)(rb + rdA0 + i * 2048);
      b0[i] = *(const bf16x8*)(rb + rdB0 + i * 2048);
    }
  }

  for (int kt = 0; kt < NT; ++kt) {
    const char* rb = lds + ((kt & 1) << 16);
    const char* rq = lds + (((kt + 1) & 1) << 16);
    if (kt + 1 < NT) STAGE(kt + 1);            // 16 gload_lds, lands during this kt
    // ---- kh0: 64 MFMA; kh1 frag reads issued ahead of each burst ----
    #pragma unroll
    for (int mi = 0; mi < 8; ++mi) {
      a1[mi] = *(const bf16x8*)(rb + ((rdA0 + mi * 2048) ^ 64));
      b1[mi] = *(const bf16x8*)(rb + ((rdB0 + mi * 2048) ^ 64));
      __builtin_amdgcn_s_setprio(1);
      #pragma unroll
      for (int ni = 0; ni < 8; ++ni)
        acc[mi][ni] = MF(a0[mi], b0[ni], acc[mi][ni]);
      __builtin_amdgcn_s_setprio(0);
    }
    // ---- kh1: 64 MFMA ----
    #pragma unroll
    for (int mi = 0; mi < 8; ++mi) {
      __builtin_amdgcn_s_setprio(1);
      #pragma unroll
      for (int ni = 0; ni < 8; ++ni)
        acc[mi][ni] = MF(a1[mi], b1[ni], acc[mi][ni]);
      __builtin_amdgcn_s_setprio(0);
    }
    if (kt + 1 < NT) {
      asm volatile("s_waitcnt vmcnt(0)");       // stage(kt+1) landed (issued ~2500 cyc ago)
      SB0();
      __builtin_amdgcn_s_barrier();             // publish to all waves; WAR separation
      SB0();
      #pragma unroll
      for (int i = 0; i < 8; ++i) {             // next tile kh0 frags
        a0[i] = *(const bf16x8*)(rq + rdA0 + i * 2048);
        b0[i] = *(const bf16x8*)(rq + rdB0 + i * 2048);
      }
    }
  }

  // epilogue: bias + direct bf16 store.  D map: col=l&15, row=(l>>4)*4+i [m89]
  const int col0 = nt * 256 + wc * 128 + fr;
  const int row0 = mt * 256 + wr * 128 + kq * 4;
  float bv[8];
  #pragma unroll
  for (int ni = 0; ni < 8; ++ni) bv[ni] = bias[(size_t)e * HID + col0 + ni * 16];
  #pragma unroll
  for (int mi = 0; mi < 8; ++mi) {
    #pragma unroll
    for (int i = 0; i < 4; ++i) {
      const int rg = row0 + mi * 16 + i;
      uint16_t* cp = C + ((size_t)e * M + rg) * HID + col0;
      #pragma unroll
      for (int ni = 0; ni < 8; ++ni)
        cp[ni * 16] = f2bf(acc[mi][ni][i] + bv[ni]);
    }
  }
}

// ---------------- LayerNorm + ReLU, in place on bf16 [E*CB][HID] ----------------
__global__ __launch_bounds__(256) void ln_relu(uint16_t* __restrict__ h,
                                               const float* __restrict__ g,
                                               const float* __restrict__ be,
                                               int kshift) {        // e = row >> kshift
  const int wid = threadIdx.x >> 6, l = threadIdx.x & 63;
  const long row = (long)blockIdx.x * 4 + wid;
  const int e = (int)(row >> kshift);
  uint16_t* p = h + row * HID;

  u16x8 s0 = *(const u16x8*)(p + l * 8);
  u16x8 s1 = *(const u16x8*)(p + 512 + l * 8);
  float v[16];
  #pragma unroll
  for (int j = 0; j < 8; ++j) { v[j] = bf2f(s0[j]); v[8 + j] = bf2f(s1[j]); }

  float sum = 0.f, sq = 0.f;
  #pragma unroll
  for (int j = 0; j < 16; ++j) { sum += v[j]; sq += v[j] * v[j]; }
  #pragma unroll
  for (int m = 1; m < 64; m <<= 1) {
    sum += __shfl_xor(sum, m);
    sq  += __shfl_xor(sq, m);
  }
  const float mu  = sum * (1.0f / HID);
  const float var = sq * (1.0f / HID) - mu * mu;
  const float rs  = rsqrtf(var + LN_EPS);

  const float* gp = g  + (size_t)e * HID;
  const float* bp = be + (size_t)e * HID;
  u16x8 o0, o1;
  #pragma unroll
  for (int j = 0; j < 8; ++j) {
    const int c0 = l * 8 + j, c1 = 512 + l * 8 + j;
    float x0 = (v[j]     - mu) * rs * gp[c0] + bp[c0];
    float x1 = (v[8 + j] - mu) * rs * gp[c1] + bp[c1];
    o0[j] = f2bf(fmaxf(x0, 0.f));
    o1[j] = f2bf(fmaxf(x1, 0.f));
  }
  *(u16x8*)(p + l * 8) = o0;
  *(u16x8*)(p + 512 + l * 8) = o1;
}

// ------- fused LN2 + ReLU + head dot + min: reads pre-LN h2, writes q/qs only -------
__global__ __launch_bounds__(256) void ln_head(const uint16_t* __restrict__ h,
                                               const float* __restrict__ g,
                                               const float* __restrict__ be,
                                               const float* __restrict__ W3,
                                               const float* __restrict__ b3,
                                               float* __restrict__ out,
                                               int b0, int CB) {
  __shared__ float qsh[EN];
  const int wv = threadIdx.x >> 6, l = threadIdx.x & 63;
  const long b = blockIdx.x;
  #pragma unroll
  for (int ee = 0; ee < 2; ++ee) {
    const int e = wv + ee * 4;
    const uint16_t* p = h + ((size_t)e * CB + b) * HID;
    u16x8 s0 = *(const u16x8*)(p + l * 8);
    u16x8 s1 = *(const u16x8*)(p + 512 + l * 8);
    float v[16];
    #pragma unroll
    for (int j = 0; j < 8; ++j) { v[j] = bf2f(s0[j]); v[8 + j] = bf2f(s1[j]); }
    float sum = 0.f, sq = 0.f;
    #pragma unroll
    for (int j = 0; j < 16; ++j) { sum += v[j]; sq += v[j] * v[j]; }
    #pragma unroll
    for (int m = 1; m < 64; m <<= 1) {
      sum += __shfl_xor(sum, m);
      sq  += __shfl_xor(sq, m);
    }
    const float mu  = sum * (1.0f / HID);
    const float var = sq * (1.0f / HID) - mu * mu;
    const float rs  = rsqrtf(var + LN_EPS);
    const float* gp = g  + (size_t)e * HID;
    const float* bp = be + (size_t)e * HID;
    const float* w  = W3 + (size_t)e * HID;
    float dot = 0.f;
    #pragma unroll
    for (int j = 0; j < 8; ++j) {
      const int c0 = l * 8 + j, c1 = 512 + l * 8 + j;
      float x0 = fmaxf((v[j]     - mu) * rs * gp[c0] + bp[c0], 0.f);
      float x1 = fmaxf((v[8 + j] - mu) * rs * gp[c1] + bp[c1], 0.f);
      dot += x0 * w[c0] + x1 * w[c1];
    }
    #pragma unroll
    for (int m = 1; m < 64; m <<= 1) dot += __shfl_xor(dot, m);
    if (l == 0) {
      const float qe = dot + b3[e];
      qsh[e] = qe;
      out[BATCH + (size_t)e * BATCH + b0 + b] = qe;   // qs
    }
  }
  __syncthreads();
  if (threadIdx.x == 0) {
    float m = qsh[0];
    #pragma unroll
    for (int i = 1; i < EN; ++i) m = fminf(m, qsh[i]);
    out[b0 + b] = m;                                   // q
  }
}

extern "C" void kernel_launch(void* const* d_in, const int* in_sizes, int n_in,
                              void* d_out, int out_size, void* d_ws, size_t ws_size,
                              hipStream_t stream) {
  const float* x   = (const float*)d_in[0];
  const float* W1  = (const float*)d_in[1];
  const float* b1  = (const float*)d_in[2];
  const float* g1  = (const float*)d_in[3];
  const float* be1 = (const float*)d_in[4];
  const float* W2  = (const float*)d_in[5];
  const float* b2  = (const float*)d_in[6];
  const float* g2  = (const float*)d_in[7];
  const float* be2 = (const float*)d_in[8];
  const float* W3  = (const float*)d_in[9];
  const float* b3  = (const float*)d_in[10];
  float* out = (float*)d_out;

  // ---- fixed workspace region: converted inputs (40 MB) ----
  char* ws = (char*)d_ws;
  uint16_t* xb  = (uint16_t*)ws; ws += (size_t)BATCH * DIN * 2;      // 16 MB
  uint16_t* w1t = (uint16_t*)ws; ws += (size_t)EN * DIN * HID * 2;   // 8 MB
  uint16_t* w2t = (uint16_t*)ws; ws += (size_t)EN * HID * HID * 2;   // 16 MB
  size_t fixed = (size_t)(ws - (char*)d_ws);

  // ---- batch-chunk size CB (power of 2, >=256) so h1+h2 fit in workspace ----
  size_t avail = (ws_size > fixed) ? (ws_size - fixed) : 0;
  const size_t per_row = 2ULL * EN * HID * 2ULL;   // h1+h2 bytes per batch row
  int CB = BATCH;
  while (CB > 256 && (size_t)CB * per_row > avail) CB >>= 1;
  const int nchunks = BATCH / CB;
  const int kshift = __builtin_ctz(CB);

  uint16_t* h1 = (uint16_t*)ws; ws += (size_t)EN * CB * HID * 2;
  uint16_t* h2 = (uint16_t*)ws;

  // ---- one-time conversions ----
  cvt_bf16<<<(BATCH * DIN / 4 + 255) / 256, 256, 0, stream>>>(x, xb, (long)BATCH * DIN);
  transpose_cvt<<<dim3(HID / 32, DIN / 32, EN), 256, 0, stream>>>(W1, w1t, DIN, HID);
  transpose_cvt<<<dim3(HID / 32, HID / 32, EN), 256, 0, stream>>>(W2, w2t, HID, HID);

  const int gblocks = (CB / 256) * (HID / 256) * EN;

  for (int c = 0; c < nchunks; ++c) {
    const int b0 = c * CB;
    gemm4w<<<gblocks, 256, 0, stream>>>(xb + (size_t)b0 * DIN, (size_t)0,
                                        w1t, b1, h1, CB, DIN);
    ln_relu<<<(EN * CB) / 4, 256, 0, stream>>>(h1, g1, be1, kshift);
    gemm4w<<<gblocks, 256, 0, stream>>>(h1, (size_t)CB * HID,
                                        w2t, b2, h2, CB, HID);
    ln_head<<<CB, 256, 0, stream>>>(h2, g2, be2, W3, b3, out, b0, CB);
  }
}